// Round 16
// baseline (219.008 us; speedup 1.0000x reference)
//
#include <hip/hip_runtime.h>
#include <cstddef>

#define TPB   256
#define NBLK  1024
#define GSTR  176
#define GSLOT (3 * GSTR)                 // 528 floats per G slot (3 staged rows)

__device__ __forceinline__ unsigned divn(unsigned f) {   // floor(f/985), valid f < 1.4e10
  return (unsigned)(((unsigned long long)f * 4465021839ULL) >> 42);
}

__device__ __forceinline__ float ldzc(const float* __restrict__ z,
                                      const float* __restrict__ dz,
                                      int row, int i) {
  const float* p = (i < 8) ? (z + (size_t)row * 8 + i)
                           : (dz + (size_t)row * 8 + (i - 8));
  return *p;
}

__device__ __forceinline__ float gval(int type, float a, float b) {
  // 0: const 1 | 1: zc | 2: pair | 3: sin | 4: zero-pad
  if (type == 2) return a * b;
  if (type == 1) return a;
  if (type == 3) return __sinf(a);
  if (type == 0) return 1.0f;
  return 0.0f;
}

__global__ __launch_bounds__(256) void sindy_kernel(const float* __restrict__ z,
                                                    const float* __restrict__ dz,
                                                    float* __restrict__ out,
                                                    int batch, int niters,
                                                    unsigned totalU) {
  __shared__ alignas(8) ushort4 qtab[985];     // unit phase -> 4x (goff | midx<<8 | inc<<13)
  __shared__ unsigned short ktab[GSTR];        // G-slot recipe
  __shared__ float G[2][GSLOT];                // double-buffered staged factors

  const int tid = threadIdx.x;
  const int bid = blockIdx.x;

  // ---- ktab: how to produce G[idx] from one row of z/dz ----
  for (int e = tid; e < GSTR; e += TPB) {
    int i = 0, j = 0, type;
    if (e == 0)        type = 0;
    else if (e < 17)  { type = 1; i = e - 1; }
    else if (e < 153) { type = 2; int p = e - 17; while (p >= 16 - i) { p -= 16 - i; ++i; } j = i + p; }
    else if (e < 169) { type = 3; i = e - 153; }
    else               type = 4;
    ktab[e] = (unsigned short)(i | (j << 4) | (type << 8));
  }

  // ---- qtab[q]: entries for the 4 cols of unit-phase q (FIXED: true mod 985) ----
  for (int q = tid; q < 985; q += TPB) {
    int c0 = 4 * q;                           // true mod: c0 in [0, 3936]
    while (c0 >= 985) c0 -= 985;
    unsigned short ent[4];
    #pragma unroll
    for (int k = 0; k < 4; ++k) {
      const int inc = (c0 + k >= 985) ? 1 : 0;   // row advances at most once per unit
      const int c   = c0 + k - inc * 985;
      unsigned goff, midx;
      if (c < 153)      { goff = (unsigned)c; midx = 0; }
      else if (c < 969) {                       // deg3 = deg2[suffix] * zc[i]
        int t = c - 153, i = 0;
        for (;;) { int cn = (16 - i) * (17 - i) / 2; if (t < cn) break; t -= cn; ++i; }
        goff = (unsigned)(17 + (136 - (16 - i) * (17 - i) / 2) + t);
        midx = (unsigned)(1 + i);
      } else { goff = (unsigned)(153 + (c - 969)); midx = 0; }
      ent[k] = (unsigned short)(goff | (midx << 8) | (inc << 13));
    }
    qtab[q] = make_ushort4(ent[0], ent[1], ent[2], ent[3]);
  }
  __syncthreads();

  // ---- per-thread staging descriptors (fixed across iters): elems tid, tid+256, tid+512 ----
  const int lr0 = tid / GSTR,  id0 = tid - lr0 * GSTR;
  const int e1i = tid + 256;
  const int lr1 = e1i / GSTR,  id1 = e1i - lr1 * GSTR;
  const bool has2 = (tid + 512 < GSLOT);        // tid < 16 -> third-row elems
  const unsigned kt0 = ktab[id0];
  const unsigned kt1 = ktab[id1];
  const unsigned kt2 = has2 ? ktab[tid + 512 - 2 * GSTR] : 0x0400u;
  const int i0 = kt0 & 15, j0 = (kt0 >> 4) & 15, ty0 = kt0 >> 8;
  const int i1 = kt1 & 15, j1 = (kt1 >> 4) & 15, ty1 = kt1 >> 8;
  const int i2 = kt2 & 15, j2 = (kt2 >> 4) & 15, ty2 = kt2 >> 8;

  // ---- prologue: stage G for it=0 into slot 0 ----
  {
    const unsigned F0 = (unsigned)bid * 1024u;
    const int rmin = (int)divn(F0);
    const int r0 = min(rmin + lr0, batch - 1);
    const int r1 = min(rmin + lr1, batch - 1);
    const int r2 = min(rmin + 2,   batch - 1);
    const float a0 = ldzc(z, dz, r0, i0), b0 = ldzc(z, dz, r0, j0);
    const float a1 = ldzc(z, dz, r1, i1), b1 = ldzc(z, dz, r1, j1);
    float a2 = 0.f, b2 = 0.f;
    if (has2) { a2 = ldzc(z, dz, r2, i2); b2 = ldzc(z, dz, r2, j2); }
    G[0][tid]       = gval(ty0, a0, b0);
    G[0][tid + 256] = gval(ty1, a1, b1);
    if (has2) G[0][tid + 512] = gval(ty2, a2, b2);
  }
  __syncthreads();

  // ---- main loop: one dense 4 MB grid-wide window per iteration ----
  for (int it = 0; it < niters; ++it) {
    const int cur = it & 1, nxt = cur ^ 1;

    // A: issue staging loads for it+1 (long-latency; covered by phase B)
    const bool dostage = (it + 1 < niters);
    float a0, b0, a1, b1, a2 = 0.f, b2 = 0.f;
    if (dostage) {
      const unsigned F0n = (unsigned)(it + 1) * 1048576u + (unsigned)bid * 1024u;
      const int rminN = (int)divn(F0n);
      const int r0 = min(rminN + lr0, batch - 1);
      const int r1 = min(rminN + lr1, batch - 1);
      const int r2 = min(rminN + 2,   batch - 1);
      a0 = ldzc(z, dz, r0, i0); b0 = ldzc(z, dz, r0, j0);
      a1 = ldzc(z, dz, r1, i1); b1 = ldzc(z, dz, r1, j1);
      if (has2) { a2 = ldzc(z, dz, r2, i2); b2 = ldzc(z, dz, r2, j2); }
    }

    // B: compute + store this thread's float4 unit (aligned, never awaited)
    const unsigned U = (unsigned)it * (NBLK * TPB) + (unsigned)bid * TPB + (unsigned)tid;
    if (U < totalU) {
      const unsigned f0   = U * 4u;
      const unsigned row0 = divn(f0);
      const unsigned q    = U - divn(U) * 985u;               // U mod 985
      const unsigned rmin = divn((unsigned)it * 1048576u + (unsigned)bid * 1024u);
      const unsigned r0b  = (row0 - rmin) * GSTR;
      const ushort4 e = qtab[q];                               // ds_read_b64
      const float* Gc = G[cur];
      float4 v;
      { const unsigned g = e.x, bb = r0b + ((g & 0x2000u) ? GSTR : 0u);
        v.x = Gc[bb + (g & 0xffu)] * Gc[bb + ((g >> 8) & 0x1fu)]; }
      { const unsigned g = e.y, bb = r0b + ((g & 0x2000u) ? GSTR : 0u);
        v.y = Gc[bb + (g & 0xffu)] * Gc[bb + ((g >> 8) & 0x1fu)]; }
      { const unsigned g = e.z, bb = r0b + ((g & 0x2000u) ? GSTR : 0u);
        v.z = Gc[bb + (g & 0xffu)] * Gc[bb + ((g >> 8) & 0x1fu)]; }
      { const unsigned g = e.w, bb = r0b + ((g & 0x2000u) ? GSTR : 0u);
        v.w = Gc[bb + (g & 0xffu)] * Gc[bb + ((g >> 8) & 0x1fu)]; }
      *(float4*)(out + (size_t)f0) = v;                        // global_store_dwordx4
    }

    // C: write staged G (counted vmcnt covers the loads; stores stay in flight)
    if (dostage) {
      G[nxt][tid]       = gval(ty0, a0, b0);
      G[nxt][tid + 256] = gval(ty1, a1, b1);
      if (has2) G[nxt][tid + 512] = gval(ty2, a2, b2);
    }

    // D: DS-only fence + raw barrier — NO vmcnt(0), stores never drained
    asm volatile("s_waitcnt lgkmcnt(0)" ::: "memory");
    __builtin_amdgcn_sched_barrier(0);
    __builtin_amdgcn_s_barrier();
    __builtin_amdgcn_sched_barrier(0);
  }
}

extern "C" void kernel_launch(void* const* d_in, const int* in_sizes, int n_in,
                              void* d_out, int out_size, void* d_ws, size_t ws_size,
                              hipStream_t stream) {
  const float* z  = (const float*)d_in[0];
  const float* dz = (const float*)d_in[1];
  float* out = (float*)d_out;
  const int batch = in_sizes[0] / 8;   // LATENT_DIM = 8

  const unsigned totalU = (unsigned)(batch / 4) * 985u;        // 32,276,480 float4 units
  const int niters = (int)((totalU + (unsigned)(NBLK * TPB) - 1) / (unsigned)(NBLK * TPB));
  sindy_kernel<<<NBLK, TPB, 0, stream>>>(z, dz, out, batch, niters, totalU);
}